// Round 1
// baseline (136.535 us; speedup 1.0000x reference)
//
#include <hip/hip_runtime.h>

#define MUL 128

__global__ __launch_bounds__(256) void tp_kernel(
    const float* __restrict__ x1, const float* __restrict__ x2,
    const float* __restrict__ w, float* __restrict__ out, int N)
{
    const float S  = 0.70710678118654752440f;  // sqrt(0.5): A0*C000, A1*C011, A1*C101, A2*C111
    const float S6 = 0.40824829046386301637f;  // sqrt(1/6):  A0*C110

    int gt = blockIdx.x * blockDim.x + threadIdx.x;
    int n  = gt >> 5;          // 32 threads per row
    if (n >= N) return;
    int t  = gt & 31;          // this thread owns u = 4t .. 4t+3

    const float* x1r = x1 + (size_t)n * (4 * MUL);

    // x1_0: 4 scalars, contiguous, 16B aligned
    float4 a0 = *reinterpret_cast<const float4*>(x1r + 4 * t);
    // x1_1: 12 contiguous floats at element offset 128 + 12t (byte 512+48t, 16B aligned)
    const float4* a1p = reinterpret_cast<const float4*>(x1r + MUL + 12 * t);
    float4 p = a1p[0], q = a1p[1], r = a1p[2];
    // x2 row: b.x = 0e scalar, (b.y,b.z,b.w) = 1o vector
    float4 b = *reinterpret_cast<const float4*>(x2 + (size_t)n * 4);

    // weights: 5 paths x 128, this thread's 4 u's (L1/L2 resident)
    float4 w0 = *reinterpret_cast<const float4*>(w + 0 * MUL + 4 * t);
    float4 w1 = *reinterpret_cast<const float4*>(w + 1 * MUL + 4 * t);
    float4 w2 = *reinterpret_cast<const float4*>(w + 2 * MUL + 4 * t);
    float4 w3 = *reinterpret_cast<const float4*>(w + 3 * MUL + 4 * t);
    float4 w4 = *reinterpret_cast<const float4*>(w + 4 * MUL + 4 * t);

    // unpack per-u (static indexing only -> stays in VGPRs)
    float a0u[4] = {a0.x, a0.y, a0.z, a0.w};
    float ax[4]  = {p.x, p.w, q.z, r.y};
    float ay[4]  = {p.y, q.x, q.w, r.z};
    float az[4]  = {p.z, q.y, r.x, r.w};
    float w0u[4] = {w0.x, w0.y, w0.z, w0.w};
    float w1u[4] = {w1.x, w1.y, w1.z, w1.w};
    float w2u[4] = {w2.x, w2.y, w2.z, w2.w};
    float w3u[4] = {w3.x, w3.y, w3.z, w3.w};
    float w4u[4] = {w4.x, w4.y, w4.z, w4.w};

    float o0[4], o1[12], o2[12];
#pragma unroll
    for (int u = 0; u < 4; ++u) {
        // 0e outputs: w0*a0*b0 + w3*(a1.b1)/sqrt(3), all scaled by A0=sqrt(.5)
        float dot = ax[u] * b.y + ay[u] * b.z + az[u] * b.w;
        o0[u] = S * w0u[u] * a0u[u] * b.x + S6 * w3u[u] * dot;
        // 1o outputs: w1*a0*b1[k] + w2*a1[k]*b0, net scale sqrt(.5)
        o1[3 * u + 0] = S * (w1u[u] * a0u[u] * b.y + w2u[u] * ax[u] * b.x);
        o1[3 * u + 1] = S * (w1u[u] * a0u[u] * b.z + w2u[u] * ay[u] * b.x);
        o1[3 * u + 2] = S * (w1u[u] * a0u[u] * b.w + w2u[u] * az[u] * b.x);
        // 1e outputs: w4 * cross(a1, b1), net scale sqrt(.5)
        float cx = ay[u] * b.w - az[u] * b.z;
        float cy = az[u] * b.y - ax[u] * b.w;
        float cz = ax[u] * b.z - ay[u] * b.y;
        o2[3 * u + 0] = S * w4u[u] * cx;
        o2[3 * u + 1] = S * w4u[u] * cy;
        o2[3 * u + 2] = S * w4u[u] * cz;
    }

    float* outr = out + (size_t)n * 896;
    *reinterpret_cast<float4*>(outr + 4 * t) = make_float4(o0[0], o0[1], o0[2], o0[3]);
    float4* o1p = reinterpret_cast<float4*>(outr + MUL + 12 * t);
    o1p[0] = make_float4(o1[0], o1[1], o1[2],  o1[3]);
    o1p[1] = make_float4(o1[4], o1[5], o1[6],  o1[7]);
    o1p[2] = make_float4(o1[8], o1[9], o1[10], o1[11]);
    float4* o2p = reinterpret_cast<float4*>(outr + 4 * MUL + 12 * t);
    o2p[0] = make_float4(o2[0], o2[1], o2[2],  o2[3]);
    o2p[1] = make_float4(o2[4], o2[5], o2[6],  o2[7]);
    o2p[2] = make_float4(o2[8], o2[9], o2[10], o2[11]);
}

extern "C" void kernel_launch(void* const* d_in, const int* in_sizes, int n_in,
                              void* d_out, int out_size, void* d_ws, size_t ws_size,
                              hipStream_t stream) {
    const float* x1  = (const float*)d_in[0];
    const float* x2  = (const float*)d_in[1];
    const float* w   = (const float*)d_in[2];
    float* out       = (float*)d_out;
    int N = in_sizes[0] / (4 * MUL);
    long long total  = (long long)N * 32;
    int blocks = (int)((total + 255) / 256);
    tp_kernel<<<blocks, 256, 0, stream>>>(x1, x2, w, out, N);
}

// Round 2
// 109.902 us; speedup vs baseline: 1.2423x; 1.2423x over previous
//
#include <hip/hip_runtime.h>

#define MUL   128
#define ROWS  8          // rows per block
#define BLOCK 256        // 32 threads per row

__global__ __launch_bounds__(BLOCK) void tp_kernel(
    const float* __restrict__ x1, const float* __restrict__ x2,
    const float* __restrict__ w, float* __restrict__ out, int N)
{
    const float S  = 0.70710678118654752440f;  // sqrt(0.5)
    const float S6 = 0.40824829046386301637f;  // sqrt(1/6)

    // One reused 28 KB buffer: first holds the x1 tile (ROWS*512 floats = 16 KB),
    // then (after all compute reads are done) the output tile (ROWS*896 floats = 28 KB).
    __shared__ float buf[ROWS * 896];

    int n0   = blockIdx.x * ROWS;
    int rows = N - n0; if (rows > ROWS) rows = ROWS;
    int tid  = threadIdx.x;

    // ---- Phase 1: stage x1 tile, fully coalesced (lane-consecutive float4) ----
    {
        const float4* src = reinterpret_cast<const float4*>(x1 + (size_t)n0 * (4 * MUL));
        float4*       dst = reinterpret_cast<float4*>(buf);
        int nf4 = rows * 128;                 // 512 floats/row = 128 float4/row
#pragma unroll
        for (int k = 0; k < 4; ++k) {
            int g = tid + k * BLOCK;
            if (g < nf4) dst[g] = src[g];
        }
    }
    __syncthreads();

    // ---- Phase 2: compute from LDS into registers ----
    int r = tid >> 5;        // row within tile
    int t = tid & 31;        // owns u = 4t .. 4t+3
    bool active = (r < rows);

    float o0[4], o1[12], o2[12];
    if (active) {
        const float* xr = buf + r * 512;
        float4 a0 = *reinterpret_cast<const float4*>(xr + 4 * t);
        const float4* a1p = reinterpret_cast<const float4*>(xr + MUL + 12 * t);
        float4 p = a1p[0], q = a1p[1], rr = a1p[2];
        // x2 row: 16 B, L1-resident (one line covers 8 rows)
        float4 b = *reinterpret_cast<const float4*>(x2 + (size_t)(n0 + r) * 4);
        // weights: 2.5 KB total, L1-resident
        float4 w0 = *reinterpret_cast<const float4*>(w + 0 * MUL + 4 * t);
        float4 w1 = *reinterpret_cast<const float4*>(w + 1 * MUL + 4 * t);
        float4 w2 = *reinterpret_cast<const float4*>(w + 2 * MUL + 4 * t);
        float4 w3 = *reinterpret_cast<const float4*>(w + 3 * MUL + 4 * t);
        float4 w4 = *reinterpret_cast<const float4*>(w + 4 * MUL + 4 * t);

        float a0u[4] = {a0.x, a0.y, a0.z, a0.w};
        float ax[4]  = {p.x, p.w, q.z, rr.y};
        float ay[4]  = {p.y, q.x, q.w, rr.z};
        float az[4]  = {p.z, q.y, rr.x, rr.w};
        float w0u[4] = {w0.x, w0.y, w0.z, w0.w};
        float w1u[4] = {w1.x, w1.y, w1.z, w1.w};
        float w2u[4] = {w2.x, w2.y, w2.z, w2.w};
        float w3u[4] = {w3.x, w3.y, w3.z, w3.w};
        float w4u[4] = {w4.x, w4.y, w4.z, w4.w};

#pragma unroll
        for (int u = 0; u < 4; ++u) {
            float dot = ax[u] * b.y + ay[u] * b.z + az[u] * b.w;
            o0[u] = S * w0u[u] * a0u[u] * b.x + S6 * w3u[u] * dot;
            o1[3 * u + 0] = S * (w1u[u] * a0u[u] * b.y + w2u[u] * ax[u] * b.x);
            o1[3 * u + 1] = S * (w1u[u] * a0u[u] * b.z + w2u[u] * ay[u] * b.x);
            o1[3 * u + 2] = S * (w1u[u] * a0u[u] * b.w + w2u[u] * az[u] * b.x);
            float cx = ay[u] * b.w - az[u] * b.z;
            float cy = az[u] * b.y - ax[u] * b.w;
            float cz = ax[u] * b.z - ay[u] * b.y;
            o2[3 * u + 0] = S * w4u[u] * cx;
            o2[3 * u + 1] = S * w4u[u] * cy;
            o2[3 * u + 2] = S * w4u[u] * cz;
        }
    }
    __syncthreads();   // all reads of buf done before overwrite

    // ---- Phase 3: outputs -> LDS (row-local layout) ----
    if (active) {
        float* orow = buf + r * 896;
        *reinterpret_cast<float4*>(orow + 4 * t) =
            make_float4(o0[0], o0[1], o0[2], o0[3]);
        float4* o1p = reinterpret_cast<float4*>(orow + MUL + 12 * t);
        o1p[0] = make_float4(o1[0], o1[1], o1[2],  o1[3]);
        o1p[1] = make_float4(o1[4], o1[5], o1[6],  o1[7]);
        o1p[2] = make_float4(o1[8], o1[9], o1[10], o1[11]);
        float4* o2p = reinterpret_cast<float4*>(orow + 4 * MUL + 12 * t);
        o2p[0] = make_float4(o2[0], o2[1], o2[2],  o2[3]);
        o2p[1] = make_float4(o2[4], o2[5], o2[6],  o2[7]);
        o2p[2] = make_float4(o2[8], o2[9], o2[10], o2[11]);
    }
    __syncthreads();

    // ---- Phase 4: store output tile, fully coalesced ----
    {
        const float4* srcb = reinterpret_cast<const float4*>(buf);
        float4*       dstg = reinterpret_cast<float4*>(out + (size_t)n0 * 896);
        int nf4 = rows * 224;                 // 896 floats/row = 224 float4/row
#pragma unroll
        for (int k = 0; k < 7; ++k) {
            int g = tid + k * BLOCK;
            if (g < nf4) dstg[g] = srcb[g];
        }
    }
}

extern "C" void kernel_launch(void* const* d_in, const int* in_sizes, int n_in,
                              void* d_out, int out_size, void* d_ws, size_t ws_size,
                              hipStream_t stream) {
    const float* x1 = (const float*)d_in[0];
    const float* x2 = (const float*)d_in[1];
    const float* w  = (const float*)d_in[2];
    float* out      = (float*)d_out;
    int N = in_sizes[0] / (4 * MUL);
    int blocks = (N + ROWS - 1) / ROWS;
    tp_kernel<<<blocks, BLOCK, 0, stream>>>(x1, x2, w, out, N);
}